// Round 6
// baseline (1785.472 us; speedup 1.0000x reference)
//
#include <hip/hip_runtime.h>
#include <math.h>

#define BDIM 64
#define NNODE 128
#define DLAT 80
#define INNER 512
#define FFD 160
#define DEPTH 24

using bf16x8 = __attribute__((ext_vector_type(8))) short;
using f32x4  = __attribute__((ext_vector_type(4))) float;

#define MFMA(a, b, c) __builtin_amdgcn_mfma_f32_16x16x32_bf16((a), (b), (c), 0, 0, 0)

static __device__ __forceinline__ short f2bf(float f) {
    union { float f; unsigned u; } v; v.f = f;
    unsigned r = v.u + 0x7fffu + ((v.u >> 16) & 1u);   // RNE
    return (short)(r >> 16);
}

__device__ __forceinline__ void wait_cnt(int* p, int target) {
    if (threadIdx.x == 0)
        while (__hip_atomic_load(p, __ATOMIC_ACQUIRE, __HIP_MEMORY_SCOPE_AGENT) < target)
            __builtin_amdgcn_s_sleep(2);
    __syncthreads();
}
__device__ __forceinline__ void arrive(int* p) {
    __syncthreads();
    if (threadIdx.x == 0)
        __hip_atomic_fetch_add(p, 1, __ATOMIC_RELEASE, __HIP_MEMORY_SCOPE_AGENT);
}

// 64x64 tile: dst[n][k] = bf16(src[k][n]), zero-pad k in [K,Kp). 512 threads.
__device__ __forceinline__ void conv_tile(
    const float* __restrict__ src, short* __restrict__ dst,
    int K, int N, int Kp, int n0, int k0, float* tbuf)
{
    int tx = threadIdx.x & 63, ty = threadIdx.x >> 6;   // ty 0..7
    for (int ki = ty; ki < 64; ki += 8) {
        int k = k0 + ki, n = n0 + tx;
        tbuf[ki * 65 + tx] = (k < K && n < N) ? src[(size_t)k * N + n] : 0.f;
    }
    __syncthreads();
    for (int ni = ty; ni < 64; ni += 8) {
        int n = n0 + ni, k = k0 + tx;
        if (n < N && k < Kp) dst[(size_t)n * Kp + k] = f2bf(tbuf[tx * 65 + ni]);
    }
    __syncthreads();
}

// LN of 32 rows held in xper -> bf16 lnx rows (row = tid>>4, sub = tid&15)
__device__ __forceinline__ void ln_rows_to_lnx(
    const float* xper, int row, int sub,
    const float* __restrict__ g, const float* __restrict__ be,
    short* __restrict__ lnxbase)
{
    float v[5];
#pragma unroll
    for (int e = 0; e < 5; ++e) v[e] = xper[row * 84 + sub * 5 + e];
    float s = v[0] + v[1] + v[2] + v[3] + v[4];
    s += __shfl_xor(s, 1); s += __shfl_xor(s, 2);
    s += __shfl_xor(s, 4); s += __shfl_xor(s, 8);
    float mean = s * 0.0125f;
    float var = 0.f;
#pragma unroll
    for (int e = 0; e < 5; ++e) { float d = v[e] - mean; var += d * d; }
    var += __shfl_xor(var, 1); var += __shfl_xor(var, 2);
    var += __shfl_xor(var, 4); var += __shfl_xor(var, 8);
    float rstd = 1.0f / sqrtf(var * 0.0125f + 1e-5f);
    short* lr = lnxbase + row * 96;
#pragma unroll
    for (int e = 0; e < 5; ++e) {
        int c = sub * 5 + e;
        lr[c] = f2bf((v[e] - mean) * rstd * g[c] + be[c]);
    }
    if (sub < 8) { lr[80 + sub * 2] = 0; lr[81 + sub * 2] = 0; }
}

// ---------------------------------------------------------------------------
// Persistent whole-network kernel. Grid 256 = (b, g), 512 threads, 1 block/CU.
// Dynamic LDS layout (bytes):
//   attn region @0..54272: qh[128][72]@0, kh[128][72]@18432, vth[64][136]@36864
//     overlays: ph[128][136]@0, ot[128][68]@36864, tbuf float[64][65]@0
//   xper float[32][84] @54272   (persistent residual rows, all layers)
//   h2s  short[32][104]@65024   (also float scratch for bias tables)
//   ffhs short[32][168]@71680
//   fin  float[256]    @82432
// total 83,456 B
// ---------------------------------------------------------------------------
__global__ __launch_bounds__(512, 2) void persist_kernel(
    const int* __restrict__ spp, const int* __restrict__ ei,
    const int* __restrict__ xn, const int* __restrict__ ind, const int* __restrict__ outd,
    const float* __restrict__ ae, const float* __restrict__ ie, const float* __restrict__ oe,
    const float* __restrict__ edge_emb, const float* __restrict__ edw,
    const float* __restrict__ sp_emb,
    const float* __restrict__ Wq, const float* __restrict__ Wkv,
    const float* __restrict__ Wo, const float* __restrict__ W1, const float* __restrict__ W2,
    const float* __restrict__ ln1_g, const float* __restrict__ ln1_b,
    const float* __restrict__ bo,
    const float* __restrict__ ln2_g, const float* __restrict__ ln2_b,
    const float* __restrict__ b1, const float* __restrict__ b2,
    const float* __restrict__ lnf_g, const float* __restrict__ lnf_b,
    const float* __restrict__ Wf, const float* __restrict__ bfp,
    float* __restrict__ biasb, short* __restrict__ lnx, short* __restrict__ obuf,
    float* __restrict__ xfin, float* __restrict__ outp,
    short* __restrict__ Wq_t, short* __restrict__ Wkv_t, short* __restrict__ Wo_t,
    short* __restrict__ W1_t, short* __restrict__ W2_t,
    int* __restrict__ flags)
{
    extern __shared__ char dyn[];
    short* qh   = (short*)dyn;               // [128][72]
    short* kh   = (short*)(dyn + 18432);     // [128][72]
    short* vth  = (short*)(dyn + 36864);     // [64][136]
    short* ph   = (short*)dyn;               // [128][136] overlay
    short* ot   = (short*)(dyn + 36864);     // [128][68] overlay
    float* tbuf = (float*)dyn;               // [64][65] overlay (phase W)
    float* xper = (float*)(dyn + 54272);     // [32][84]
    short* h2s  = (short*)(dyn + 65024);     // [32][104]
    short* ffhs = (short*)(dyn + 71680);     // [32][168]
    float* fin  = (float*)(dyn + 82432);     // [256]

    int tid = threadIdx.x;
    int lane = tid & 63, w = tid >> 6, l15 = lane & 15, lk = lane >> 4;
    int bid = blockIdx.x;
    int b = bid >> 2, g = bid & 3;
    int R0 = g * 32;

    int* ca = flags + b * DEPTH;                 // attn counters [24]
    int* ct = flags + 1536 + b * (DEPTH + 1);    // tail counters [25]
    int* wflag = flags + 3136;

    // ======== phase W: weight convert/transpose (grid-strided tiles) ========
#pragma unroll 1
    for (int t = bid; t < 1824; t += 256) {
        if (t < 384) {
            int L = t >> 4, r = t & 15;
            conv_tile(Wq + (size_t)L * 80 * 512, Wq_t + (size_t)L * 512 * 96,
                      80, 512, 96, (r >> 1) * 64, (r & 1) * 64, tbuf);
        } else if (t < 1152) {
            int u = t - 384; int L = u >> 5, r = u & 31;
            conv_tile(Wkv + (size_t)L * 80 * 1024, Wkv_t + (size_t)L * 1024 * 96,
                      80, 1024, 96, (r >> 1) * 64, (r & 1) * 64, tbuf);
        } else if (t < 1536) {
            int u = t - 1152; int L = u >> 4, r = u & 15;
            conv_tile(Wo + (size_t)L * 512 * 80, Wo_t + (size_t)L * 80 * 512,
                      512, 80, 512, (r & 1) * 64, (r >> 1) * 64, tbuf);
        } else if (t < 1680) {
            int u = t - 1536; int L = u / 6, r = u % 6;
            conv_tile(W1 + (size_t)L * 80 * 160, W1_t + (size_t)L * 160 * 96,
                      80, 160, 96, (r % 3) * 64, (r / 3) * 64, tbuf);
        } else {
            int u = t - 1680; int L = u / 6, r = u % 6;
            conv_tile(W2 + (size_t)L * 160 * 80, W2_t + (size_t)L * 80 * 160,
                      160, 80, 160, (r & 1) * 64, (r / 2) * 64, tbuf);
        }
    }
    if (tid == 0)
        __hip_atomic_fetch_add(wflag, 1, __ATOMIC_RELEASE, __HIP_MEMORY_SCOPE_AGENT);

    // ======== phase 0a: structural bias for own 32 rows of b ========
    {
        float* ee = (float*)h2s;          // 64
        float* ew = ee + 64;              // 20
        float* se = ee + 84;              // 40
        if (tid < 64) ee[tid] = edge_emb[tid];
        else if (tid < 84) ew[tid - 64] = edw[tid - 64];
        else if (tid < 124) se[tid - 84] = sp_emb[tid - 84];
        __syncthreads();
        size_t base = ((size_t)b * NNODE + R0) * NNODE + (size_t)tid * 8;
#pragma unroll 1
        for (int u = 0; u < 8; ++u) {
            size_t idx = base + u;
            int spv = spp[idx];
            float spb = se[spv];
            int sp = min(20, max(1, spv - 1));
            const int4* p = (const int4*)(ei + idx * 60);
            int e[60];
#pragma unroll
            for (int t4 = 0; t4 < 15; ++t4) {
                int4 v = p[t4];
                e[4*t4+0] = v.x; e[4*t4+1] = v.y; e[4*t4+2] = v.z; e[4*t4+3] = v.w;
            }
            float acc = 0.f;
#pragma unroll
            for (int m = 0; m < 20; ++m) {
                float s3 = ee[e[3*m]] + ee[e[3*m+1]] + ee[e[3*m+2]];
                acc += s3 * ew[m];
            }
            biasb[idx] = acc * (1.0f/3.0f) / (float)sp + spb;
        }
        __syncthreads();   // h2s scratch free
    }

    // ======== phase 0b: embeddings -> xper, LN1(layer 0) -> lnx ========
    {
        int row = tid >> 4, sub = tid & 15;
        int node = b * NNODE + R0 + row;
        int xv = xn[node] * DLAT, iv = ind[node] * DLAT, ov = outd[node] * DLAT;
#pragma unroll
        for (int e = 0; e < 5; ++e) {
            int c = sub * 5 + e;
            xper[row * 84 + c] = ae[xv + c] + ie[iv + c] + oe[ov + c];
        }
        __syncthreads();
        ln_rows_to_lnx(xper, row, sub, ln1_g, ln1_b, lnx + ((size_t)b * NNODE + R0) * 96);
    }
    arrive(ct + 0);
    wait_cnt(ct + 0, 4);          // siblings' bias+lnx ready
    wait_cnt(wflag, 256);         // all weights converted

    // bias registers, layer-invariant: rows w*16+lk*4+r, cols jf*16+l15
    float breg[8][4];
    {
        const float* bp = biasb + ((size_t)b * NNODE + w * 16) * NNODE;
#pragma unroll
        for (int jf = 0; jf < 8; ++jf)
#pragma unroll
            for (int r = 0; r < 4; ++r)
                breg[jf][r] = bp[(lk * 4 + r) * NNODE + jf * 16 + l15];
    }

    // ======== layer loop ========
#pragma unroll 1
    for (int L = 0; L < DEPTH; ++L) {
        const short* WqL  = Wq_t  + (size_t)L * INNER * 96;
        const short* WkvL = Wkv_t + (size_t)L * 1024 * 96;
        const short* WoL  = Wo_t  + (size_t)L * DLAT * INNER;
        const short* W1L  = W1_t  + (size_t)L * FFD * 96;
        const short* W2L  = W2_t  + (size_t)L * DLAT * FFD;
        const float* boL  = bo + L * DLAT;
        const float* g2L  = ln2_g + L * DLAT;
        const float* be2L = ln2_b + L * DLAT;
        const float* b1L  = b1 + L * FFD;
        const float* b2L  = b2 + L * DLAT;

        // -------- attn phase: heads 2g, 2g+1; wave w owns rows w*16..+15 ----
        if (L > 0) wait_cnt(ct + L, 4);
        bf16x8 av0, av1, av2;
        {
            const short* lb = lnx + (size_t)b * NNODE * 96 + (w * 16 + l15) * 96 + lk * 8;
            av0 = *(const bf16x8*)(lb);
            av1 = *(const bf16x8*)(lb + 32);
            av2 = *(const bf16x8*)(lb + 64);
        }
        bf16x8 av[3] = {av0, av1, av2};
#pragma unroll 1
        for (int hh = 0; hh < 2; ++hh) {
            int h = g * 2 + hh;
            if (hh) __syncthreads();   // ot reads of prev head done before vth writes
            // Q -> qh
            {
                f32x4 acc[4] = {};
#pragma unroll
                for (int ss = 0; ss < 3; ++ss) {
                    const short* wp = WqL + (size_t)(h * 64 + l15) * 96 + ss * 32 + lk * 8;
#pragma unroll
                    for (int nf = 0; nf < 4; ++nf)
                        acc[nf] = MFMA(av[ss], *(const bf16x8*)(wp + nf * 16 * 96), acc[nf]);
                }
#pragma unroll
                for (int nf = 0; nf < 4; ++nf)
#pragma unroll
                    for (int r = 0; r < 4; ++r)
                        qh[(w * 16 + lk * 4 + r) * 72 + nf * 16 + l15] = f2bf(acc[nf][r]);
            }
            // K -> kh
            {
                f32x4 acc[4] = {};
#pragma unroll
                for (int ss = 0; ss < 3; ++ss) {
                    const short* wp = WkvL + (size_t)(h * 64 + l15) * 96 + ss * 32 + lk * 8;
#pragma unroll
                    for (int nf = 0; nf < 4; ++nf)
                        acc[nf] = MFMA(av[ss], *(const bf16x8*)(wp + nf * 16 * 96), acc[nf]);
                }
#pragma unroll
                for (int nf = 0; nf < 4; ++nf)
#pragma unroll
                    for (int r = 0; r < 4; ++r)
                        kh[(w * 16 + lk * 4 + r) * 72 + nf * 16 + l15] = f2bf(acc[nf][r]);
            }
            // V -> vth (transposed)
            {
                f32x4 acc[4] = {};
#pragma unroll
                for (int ss = 0; ss < 3; ++ss) {
                    const short* wp = WkvL + (size_t)(INNER + h * 64 + l15) * 96 + ss * 32 + lk * 8;
#pragma unroll
                    for (int nf = 0; nf < 4; ++nf)
                        acc[nf] = MFMA(av[ss], *(const bf16x8*)(wp + nf * 16 * 96), acc[nf]);
                }
#pragma unroll
                for (int nf = 0; nf < 4; ++nf)
#pragma unroll
                    for (int r = 0; r < 4; ++r)
                        vth[(nf * 16 + l15) * 136 + w * 16 + lk * 4 + r] = f2bf(acc[nf][r]);
            }
            __syncthreads();

            // QK^T
            f32x4 sc[8] = {};
#pragma unroll
            for (int ss = 0; ss < 2; ++ss) {
                bf16x8 qa = *(const bf16x8*)(qh + (w * 16 + l15) * 72 + ss * 32 + lk * 8);
#pragma unroll
                for (int jf = 0; jf < 8; ++jf)
                    sc[jf] = MFMA(qa, *(const bf16x8*)(kh + (jf * 16 + l15) * 72 + ss * 32 + lk * 8), sc[jf]);
            }
            __syncthreads();   // qh/kh reads done before ph overlay writes

            // softmax + P -> ph
            float rinv[4];
#pragma unroll
            for (int r = 0; r < 4; ++r) {
                float sv[8];
#pragma unroll
                for (int jf = 0; jf < 8; ++jf) sv[jf] = sc[jf][r] * 0.125f + breg[jf][r];
                float mx = sv[0];
#pragma unroll
                for (int jf = 1; jf < 8; ++jf) mx = fmaxf(mx, sv[jf]);
                mx = fmaxf(mx, __shfl_xor(mx, 1));
                mx = fmaxf(mx, __shfl_xor(mx, 2));
                mx = fmaxf(mx, __shfl_xor(mx, 4));
                mx = fmaxf(mx, __shfl_xor(mx, 8));
                float e[8], sum = 0.f;
#pragma unroll
                for (int jf = 0; jf < 8; ++jf) { e[jf] = __expf(sv[jf] - mx); sum += e[jf]; }
                sum += __shfl_xor(sum, 1);
                sum += __shfl_xor(sum, 2);
                sum += __shfl_xor(sum, 4);
                sum += __shfl_xor(sum, 8);
                rinv[r] = 1.0f / sum;
                int row = w * 16 + lk * 4 + r;
#pragma unroll
                for (int jf = 0; jf < 8; ++jf)
                    ph[row * 136 + jf * 16 + l15] = f2bf(e[jf]);
            }
            __syncthreads();

            // PV
            f32x4 o[4] = {};
#pragma unroll
            for (int ks = 0; ks < 4; ++ks) {
                bf16x8 pa = *(const bf16x8*)(ph + (w * 16 + l15) * 136 + ks * 32 + lk * 8);
#pragma unroll
                for (int nf = 0; nf < 4; ++nf)
                    o[nf] = MFMA(pa, *(const bf16x8*)(vth + (nf * 16 + l15) * 136 + ks * 32 + lk * 8), o[nf]);
            }
            __syncthreads();   // vth reads done before ot overlay writes

#pragma unroll
            for (int nf = 0; nf < 4; ++nf)
#pragma unroll
                for (int r = 0; r < 4; ++r)
                    ot[(w * 16 + lk * 4 + r) * 68 + nf * 16 + l15] = f2bf(o[nf][r] * rinv[r]);
            __syncthreads();

            // coalesced obuf store
            {
                int row = tid >> 2, q4 = tid & 3;
                const short* src = ot + row * 68 + q4 * 16;
                short* dst = obuf + ((size_t)b * NNODE + row) * INNER + h * 64 + q4 * 16;
#pragma unroll
                for (int qq = 0; qq < 4; ++qq)
                    *(uint2*)(dst + qq * 4) = *(const uint2*)(src + qq * 4);
            }
        }
        arrive(ca + L);

        // -------- tail phase: own quarter rows R0..R0+31 ----
        wait_cnt(ca + L, 4);
        {
            int wr = w >> 2, wn = w & 3;
            int n0_5 = (wn == 0) ? 0 : (wn + 1), nc_5 = (wn == 0) ? 2 : 1;
            int n0_10 = (wn < 2) ? wn * 3 : 6 + (wn - 2) * 2, nc_10 = (wn < 2) ? 3 : 2;

            // O-proj + bo + residual (xper RMW)
            {
                const short* og = obuf + ((size_t)b * NNODE + R0) * INNER;
                f32x4 acc[2] = {};
#pragma unroll 4
                for (int ks = 0; ks < 16; ++ks) {
                    bf16x8 aa = *(const bf16x8*)(og + (wr * 16 + l15) * INNER + lk * 8 + ks * 32);
#pragma unroll
                    for (int j = 0; j < 2; ++j)
                        if (j < nc_5) {
                            bf16x8 bv = *(const bf16x8*)(WoL + (size_t)((n0_5 + j) * 16 + l15) * INNER + lk * 8 + ks * 32);
                            acc[j] = MFMA(aa, bv, acc[j]);
                        }
                }
#pragma unroll
                for (int j = 0; j < 2; ++j)
                    if (j < nc_5)
#pragma unroll
                        for (int r = 0; r < 4; ++r) {
                            int row = wr * 16 + lk * 4 + r, col = (n0_5 + j) * 16 + l15;
                            xper[row * 84 + col] += acc[j][r] + boL[col];
                        }
            }
            __syncthreads();

            // LN2 -> h2s
            {
                int row = tid >> 4, sub = tid & 15;
                float v[5];
#pragma unroll
                for (int e = 0; e < 5; ++e) v[e] = xper[row * 84 + sub * 5 + e];
                float s = v[0] + v[1] + v[2] + v[3] + v[4];
                s += __shfl_xor(s, 1); s += __shfl_xor(s, 2);
                s += __shfl_xor(s, 4); s += __shfl_xor(s, 8);
                float mean = s * 0.0125f;
                float var = 0.f;
#pragma unroll
                for (int e = 0; e < 5; ++e) { float d = v[e] - mean; var += d * d; }
                var += __shfl_xor(var, 1); var += __shfl_xor(var, 2);
                var += __shfl_xor(var, 4); var += __shfl_xor(var, 8);
                float rstd = 1.0f / sqrtf(var * 0.0125f + 1e-5f);
#pragma unroll
                for (int e = 0; e < 5; ++e) {
                    int c = sub * 5 + e;
                    h2s[row * 104 + c] = f2bf((v[e] - mean) * rstd * g2L[c] + be2L[c]);
                }
                if (sub < 4) {
                    short4 z4; z4.x = z4.y = z4.z = z4.w = 0;
                    *(short4*)(h2s + row * 104 + 80 + sub * 4) = z4;
                }
            }
            __syncthreads();

            // FF1 + GELU -> ffhs
            {
                f32x4 acc[3] = {};
#pragma unroll
                for (int ss = 0; ss < 3; ++ss) {
                    bf16x8 aa = *(const bf16x8*)(h2s + (wr * 16 + l15) * 104 + lk * 8 + ss * 32);
#pragma unroll
                    for (int j = 0; j < 3; ++j)
                        if (j < nc_10) {
                            bf16x8 bv = *(const bf16x8*)(W1L + (size_t)((n0_10 + j) * 16 + l15) * 96 + lk * 8 + ss * 32);
                            acc[j] = MFMA(aa, bv, acc[j]);
                        }
                }
#pragma unroll
                for (int j = 0; j < 3; ++j)
                    if (j < nc_10)
#pragma unroll
                        for (int r = 0; r < 4; ++r) {
                            int row = wr * 16 + lk * 4 + r, c = (n0_10 + j) * 16 + l15;
                            float vv = acc[j][r] + b1L[c];
                            vv = 0.5f * vv * (1.0f + erff(vv * 0.70710678118654752f));
                            ffhs[row * 168 + c] = f2bf(vv);
                        }
            }
            __syncthreads();

            // FF2 + b2 + residual -> xper (+ xfin at last layer)
            {
                f32x4 acc[2] = {};
#pragma unroll
                for (int ks = 0; ks < 5; ++ks) {
                    bf16x8 aa = *(const bf16x8*)(ffhs + (wr * 16 + l15) * 168 + lk * 8 + ks * 32);
#pragma unroll
                    for (int j = 0; j < 2; ++j)
                        if (j < nc_5) {
                            bf16x8 bv = *(const bf16x8*)(W2L + (size_t)((n0_5 + j) * 16 + l15) * FFD + lk * 8 + ks * 32);
                            acc[j] = MFMA(aa, bv, acc[j]);
                        }
                }
#pragma unroll
                for (int j = 0; j < 2; ++j)
                    if (j < nc_5)
#pragma unroll
                        for (int r = 0; r < 4; ++r) {
                            int row = wr * 16 + lk * 4 + r, col = (n0_5 + j) * 16 + l15;
                            float vv = acc[j][r] + b2L[col] + xper[row * 84 + col];
                            xper[row * 84 + col] = vv;
                            if (L == DEPTH - 1)
                                xfin[((size_t)b * NNODE + R0 + row) * DLAT + col] = vv;
                        }
            }
            __syncthreads();

            // LN1 of next layer -> lnx
            if (L < DEPTH - 1) {
                int row = tid >> 4, sub = tid & 15;
                ln_rows_to_lnx(xper, row, sub,
                               ln1_g + (L + 1) * DLAT, ln1_b + (L + 1) * DLAT,
                               lnx + ((size_t)b * NNODE + R0) * 96);
            }
        }
        arrive(ct + L + 1);
    }

    // ======== final: mean over nodes -> LN -> @Wf + bf (block g==0 per b) ====
    if (g == 0) {
        wait_cnt(ct + DEPTH, 4);
        float* pd = fin;          // 80
        float* red = fin + 80;    // 2
        float* rb = fin + 82;     // 80
        if (tid < DLAT) {
            float s = 0.f;
#pragma unroll 1
            for (int n = 0; n < NNODE; ++n)
                s += xfin[((size_t)b * NNODE + n) * DLAT + tid];
            pd[tid] = s * (1.0f / NNODE);
        }
        __syncthreads();
        if (tid == 0) {
            float m = 0.f;
            for (int k = 0; k < DLAT; ++k) m += pd[k];
            m /= DLAT;
            float v = 0.f;
            for (int k = 0; k < DLAT; ++k) { float d = pd[k] - m; v += d * d; }
            v /= DLAT;
            red[0] = m; red[1] = 1.0f / sqrtf(v + 1e-5f);
        }
        __syncthreads();
        if (tid < DLAT)
            rb[tid] = ((pd[tid] - red[0]) * red[1] * lnf_g[tid] + lnf_b[tid]) * Wf[tid];
        __syncthreads();
        if (tid == 0) {
            float s = 0.f;
            for (int k = 0; k < DLAT; ++k) s += rb[k];
            outp[b] = s + bfp[0];
        }
    }
}

// ---------------------------------------------------------------------------
extern "C" void kernel_launch(void* const* d_in, const int* in_sizes, int n_in,
                              void* d_out, int out_size, void* d_ws, size_t ws_size,
                              hipStream_t stream)
{
    const int*   spatial_pos = (const int*)  d_in[0];
    const int*   edge_input  = (const int*)  d_in[1];
    const int*   x_nodes     = (const int*)  d_in[2];
    const int*   indeg       = (const int*)  d_in[3];
    const int*   outdeg      = (const int*)  d_in[4];
    const float* atom_emb    = (const float*)d_in[5];
    const float* indeg_emb   = (const float*)d_in[6];
    const float* outdeg_emb  = (const float*)d_in[7];
    const float* edge_emb    = (const float*)d_in[8];
    const float* edge_dis_w  = (const float*)d_in[9];
    const float* spatial_emb = (const float*)d_in[10];
    const float* ln1_g = (const float*)d_in[11];
    const float* ln1_b = (const float*)d_in[12];
    const float* Wq    = (const float*)d_in[13];
    const float* Wkv   = (const float*)d_in[14];
    const float* Wo    = (const float*)d_in[15];
    const float* bo    = (const float*)d_in[16];
    const float* ln2_g = (const float*)d_in[17];
    const float* ln2_b = (const float*)d_in[18];
    const float* W1    = (const float*)d_in[19];
    const float* b1    = (const float*)d_in[20];
    const float* W2    = (const float*)d_in[21];
    const float* b2    = (const float*)d_in[22];
    const float* lnf_g = (const float*)d_in[23];
    const float* lnf_b = (const float*)d_in[24];
    const float* Wf    = (const float*)d_in[25];
    const float* bf    = (const float*)d_in[26];

    char* wsb = (char*)d_ws;
    float* biasb = (float*)(wsb + 0);           //  4,194,304
    float* xfin  = (float*)(wsb + 4194304);     //  2,621,440
    short* obuf  = (short*)(wsb + 9437184);     //  8,388,608
    short* Wq_t  = (short*)(wsb + 17825792);    //  2,359,296  [512][96]/layer
    short* Wkv_t = (short*)(wsb + 20185088);    //  4,718,592  [1024][96]/layer
    short* Wo_t  = (short*)(wsb + 24903680);    //  1,966,080  [80][512]/layer
    short* W1_t  = (short*)(wsb + 26869760);    //    737,280  [160][96]/layer
    short* W2_t  = (short*)(wsb + 27607040);    //    614,400  [80][160]/layer
    short* lnx   = (short*)(wsb + 28221440);    //  1,572,864  [8192][96]
    int*   flags = (int*)  (wsb + 29794304);    //     12,548  ca|ct|wflag

    static const int LDSB = 83456;
    hipFuncSetAttribute((const void*)persist_kernel,
                        hipFuncAttributeMaxDynamicSharedMemorySize, LDSB);

    hipMemsetAsync(flags, 0, 12548, stream);

    persist_kernel<<<256, 512, LDSB, stream>>>(
        spatial_pos, edge_input, x_nodes, indeg, outdeg,
        atom_emb, indeg_emb, outdeg_emb, edge_emb, edge_dis_w, spatial_emb,
        Wq, Wkv, Wo, W1, W2,
        ln1_g, ln1_b, bo, ln2_g, ln2_b, b1, b2,
        lnf_g, lnf_b, Wf, bf,
        biasb, lnx, obuf, xfin, (float*)d_out,
        Wq_t, Wkv_t, Wo_t, W1_t, W2_t,
        flags);
}